// Round 1
// baseline (679.650 us; speedup 1.0000x reference)
//
#include <hip/hip_runtime.h>
#include <hip/hip_fp16.h>

// ---------- types ----------
typedef __bf16 bf16x8 __attribute__((ext_vector_type(8)));
typedef float  f32x4  __attribute__((ext_vector_type(4)));
typedef _Float16 half2v __attribute__((ext_vector_type(2)));
typedef unsigned short ushort8 __attribute__((ext_vector_type(8)));

// float -> bf16 RNE (finite inputs)
__device__ __forceinline__ unsigned short f2bf(float f){
  unsigned u = __builtin_bit_cast(unsigned, f);
  u = (u + 0x7FFFu + ((u >> 16) & 1u)) >> 16;
  return (unsigned short)u;
}

#if defined(__has_builtin)
#  if __has_builtin(__builtin_amdgcn_fdot2)
#    define FDOT2(a,b,c) __builtin_amdgcn_fdot2((a),(b),(c),false)
#  endif
#endif
#ifndef FDOT2
__device__ __forceinline__ float fdot2_sw(half2v a, half2v b, float c){
  return c + (float)a[0]*(float)b[0] + (float)a[1]*(float)b[1];
}
#  define FDOT2(a,b,c) fdot2_sw((a),(b),(c))
#endif

__device__ __forceinline__ float gelu_exact(float x){
  return 0.5f * x * (1.0f + erff(0.70710678118654752f * x));
}

// ---------- kernel 0: pack mix_w into MFMA B-fragment order (bf16) ----------
// Wt[K=j*16+d][N=i*16+k] = mix_w[i][j][k][d];  frag f = ntile*4 + kstep,
// lane L holds B[k = kstep*32 + (L>>4)*8 + j][n = ntile*16 + (L&15)], j=0..7.
__global__ void prepack_wt(const float* __restrict__ mix_w,
                           unsigned short* __restrict__ wt){
  int tid = blockIdx.x * 256 + threadIdx.x;      // 0..2047
  int f = tid >> 6, L = tid & 63;
  int ks = f & 3, nt = f >> 2;
  int q = L >> 4, c = L & 15;
  int N = nt * 16 + c;
  int i = N >> 4, ko = N & 15;
  unsigned pk[4];
#pragma unroll
  for (int p = 0; p < 4; ++p){
    int K0 = ks * 32 + q * 8 + 2 * p;
    int K1 = K0 + 1;
    unsigned lo = f2bf(mix_w[((i*8 + (K0>>4))*16 + ko)*16 + (K0&15)]);
    unsigned hi = f2bf(mix_w[((i*8 + (K1>>4))*16 + ko)*16 + (K1&15)]);
    pk[p] = lo | (hi << 16);
  }
  uint4 v; v.x = pk[0]; v.y = pk[1]; v.z = pk[2]; v.w = pk[3];
  ((uint4*)wt)[tid] = v;
}

// ---------- main fused kernel: 64 rows per block, 256 threads (4 waves) ----------
__global__ __launch_bounds__(256, 2)
void soft_eq_kernel(const float* __restrict__ z,
                    const float* __restrict__ w1,  const float* __restrict__ b1,
                    const float* __restrict__ w2,  const float* __restrict__ b2,
                    const float* __restrict__ w3,  const float* __restrict__ gate_bias,
                    const unsigned short* __restrict__ wt,
                    float* __restrict__ out){
  __shared__ float    zsm[64][132];     // padded stride: bank-spread for frag reads
  __shared__ float    normsS[64][8];
  __shared__ float    scalesS[64][8];
  __shared__ _Float16 h1s[64][64];
  __shared__ _Float16 h2s[64][72];      // pad 72: conflict-free MLP3 b128 reads
  __shared__ float    gatesS[8];

  const int t = threadIdx.x;
  const size_t base = (size_t)blockIdx.x * (64 * 128);
  const float4* zg = (const float4*)(z + base);

  // ---- stage z into LDS (fp32) + per-bundle norms via lane shuffles ----
#pragma unroll
  for (int it = 0; it < 8; ++it){
    int idx = t + it * 256;             // float4 index in [0,2048)
    float4 v = zg[idx];
    int r  = idx >> 5;                  // row in tile
    int c4 = (idx & 31) * 4;            // col (multiple of 4)
    *(float4*)&zsm[r][c4] = v;
    float ss = v.x*v.x + v.y*v.y + v.z*v.z + v.w*v.w;
    ss += __shfl_xor(ss, 1);
    ss += __shfl_xor(ss, 2);
    if ((t & 3) == 0) normsS[r][c4 >> 4] = sqrtf(ss) + 1e-8f;
  }

  // ---- register-cache per-neuron weight rows (L1-resident) ----
  const int i = t & 63;                 // neuron id for MLP1/2
  float w1r[8];
  { const float4* p = (const float4*)(w1 + i * 8);
    float4 a = p[0], bq = p[1];
    w1r[0]=a.x; w1r[1]=a.y; w1r[2]=a.z; w1r[3]=a.w;
    w1r[4]=bq.x; w1r[5]=bq.y; w1r[6]=bq.z; w1r[7]=bq.w; }
  const float b1r = b1[i], b2r = b2[i];
  half2v wreg[32];                      // w2 row (later reused for w3 row)
  { const float4* p = (const float4*)(w2 + i * 64);
#pragma unroll
    for (int kk = 0; kk < 16; ++kk){
      float4 v = p[kk];
      wreg[2*kk]   = half2v{(_Float16)v.x, (_Float16)v.y};
      wreg[2*kk+1] = half2v{(_Float16)v.z, (_Float16)v.w};
    } }
  if (t < 8) gatesS[t] = 1.0f / (1.0f + expf(-gate_bias[t]));

  __syncthreads();

  // ---- MLP layer 1: h1 = gelu(norms @ w1^T + b1) ----
  const int rg = t >> 6;                // row-subgroup 0..3
#pragma unroll
  for (int chunk = 0; chunk < 16; ++chunk){
    int r = chunk * 4 + rg;
    const float4* np = (const float4*)&normsS[r][0];   // broadcast reads
    float4 n0 = np[0], n1 = np[1];
    float pre = b1r + n0.x*w1r[0] + n0.y*w1r[1] + n0.z*w1r[2] + n0.w*w1r[3]
                    + n1.x*w1r[4] + n1.y*w1r[5] + n1.z*w1r[6] + n1.w*w1r[7];
    h1s[r][i] = (_Float16)gelu_exact(pre);
  }
  __syncthreads();

  // ---- MLP layer 2: h2 = gelu(h1 @ w2^T + b2), f16 dot2 ----
#pragma unroll
  for (int chunk = 0; chunk < 16; ++chunk){
    int r = chunk * 4 + rg;
    float accv = b2r;
    const uint4* hp = (const uint4*)&h1s[r][0];        // broadcast b128 reads
#pragma unroll
    for (int kk = 0; kk < 8; ++kk){
      uint4 hv = hp[kk];
      accv = FDOT2(__builtin_bit_cast(half2v, hv.x), wreg[4*kk+0], accv);
      accv = FDOT2(__builtin_bit_cast(half2v, hv.y), wreg[4*kk+1], accv);
      accv = FDOT2(__builtin_bit_cast(half2v, hv.z), wreg[4*kk+2], accv);
      accv = FDOT2(__builtin_bit_cast(half2v, hv.w), wreg[4*kk+3], accv);
    }
    h2s[r][i] = (_Float16)gelu_exact(accv);
  }

  // reload wreg with this thread's w3 row (register live-range reuse)
  { const float4* p = (const float4*)(w3 + (t & 7) * 64);
#pragma unroll
    for (int kk = 0; kk < 16; ++kk){
      float4 v = p[kk];
      wreg[2*kk]   = half2v{(_Float16)v.x, (_Float16)v.y};
      wreg[2*kk+1] = half2v{(_Float16)v.z, (_Float16)v.w};
    } }
  __syncthreads();

  // ---- MLP layer 3: scales = softplus(h2 @ w3^T) ----
#pragma unroll
  for (int s = 0; s < 2; ++s){
    int item = s * 256 + t;
    int r = item >> 3, j = item & 7;
    float accv = 0.0f;
    const uint4* hp = (const uint4*)&h2s[r][0];
#pragma unroll
    for (int kk = 0; kk < 8; ++kk){
      uint4 hv = hp[kk];
      accv = FDOT2(__builtin_bit_cast(half2v, hv.x), wreg[4*kk+0], accv);
      accv = FDOT2(__builtin_bit_cast(half2v, hv.y), wreg[4*kk+1], accv);
      accv = FDOT2(__builtin_bit_cast(half2v, hv.z), wreg[4*kk+2], accv);
      accv = FDOT2(__builtin_bit_cast(half2v, hv.w), wreg[4*kk+3], accv);
    }
    // stable softplus = max(x,0) + log1p(exp(-|x|))
    scalesS[r][j] = fmaxf(accv, 0.0f) + log1pf(expf(-fabsf(accv)));
  }
  __syncthreads();

  // ---- mixing GEMM: wave w owns rows 16w..16w+15; C = Ztile @ Wt ----
  const int w = t >> 6, L = t & 63, q = L >> 4, c = L & 15;
  f32x4 acc[8] = {};                    // 8 n-tiles x 4 fp32
  const uint4* wtf = (const uint4*)wt;
  const int am = w * 16 + c;            // A row (m = lane&15)
#pragma unroll
  for (int ks = 0; ks < 4; ++ks){
    int ak = ks * 32 + q * 8;           // A k-base (contiguous 8)
    float4 a0 = *(const float4*)&zsm[am][ak];
    float4 a1 = *(const float4*)&zsm[am][ak + 4];
    ushort8 au;
    au[0]=f2bf(a0.x); au[1]=f2bf(a0.y); au[2]=f2bf(a0.z); au[3]=f2bf(a0.w);
    au[4]=f2bf(a1.x); au[5]=f2bf(a1.y); au[6]=f2bf(a1.z); au[7]=f2bf(a1.w);
    bf16x8 af = __builtin_bit_cast(bf16x8, au);
#pragma unroll
    for (int n = 0; n < 8; ++n){
      uint4 bv = wtf[(n * 4 + ks) * 64 + L];           // L1-hit, coalesced
      bf16x8 bfr = __builtin_bit_cast(bf16x8, bv);
      acc[n] = __builtin_amdgcn_mfma_f32_16x16x32_bf16(af, bfr, acc[n], 0, 0, 0);
    }
  }

  // ---- epilogue straight from MFMA C-layout (wave-private rows) ----
  float* op = out + base;
#pragma unroll
  for (int n = 0; n < 8; ++n){          // n == bundle index of output col
    float gate = gatesS[n];
#pragma unroll
    for (int rr = 0; rr < 4; ++rr){
      int row = w * 16 + q * 4 + rr;    // C row = (lane>>4)*4 + reg
      int col = n * 16 + c;             // C col = lane&15
      float zv = zsm[row][col];
      float sc = scalesS[row][n];
      op[row * 128 + col] = zv + zv * sc + gate * acc[n][rr];
    }
  }
}

extern "C" void kernel_launch(void* const* d_in, const int* in_sizes, int n_in,
                              void* d_out, int out_size, void* d_ws, size_t ws_size,
                              hipStream_t stream){
  const float* z         = (const float*)d_in[0];
  const float* w1        = (const float*)d_in[1];
  const float* b1        = (const float*)d_in[2];
  const float* w2        = (const float*)d_in[3];
  const float* b2        = (const float*)d_in[4];
  const float* w3        = (const float*)d_in[5];
  const float* mix_w     = (const float*)d_in[6];
  const float* gate_bias = (const float*)d_in[7];
  float* out = (float*)d_out;
  unsigned short* wt = (unsigned short*)d_ws;   // 32 KiB B-fragment cache

  int B = in_sizes[0] / 128;                    // rows
  prepack_wt<<<8, 256, 0, stream>>>(mix_w, wt);
  soft_eq_kernel<<<B / 64, 256, 0, stream>>>(z, w1, b1, w2, b2, w3, gate_bias, wt, out);
}

// Round 2
// 608.109 us; speedup vs baseline: 1.1176x; 1.1176x over previous
//
#include <hip/hip_runtime.h>
#include <hip/hip_fp16.h>

// ---------- types ----------
typedef __bf16 bf16x8 __attribute__((ext_vector_type(8)));
typedef float  f32x4  __attribute__((ext_vector_type(4)));
typedef _Float16 half2v __attribute__((ext_vector_type(2)));
typedef unsigned short ushort8 __attribute__((ext_vector_type(8)));

// float -> bf16 RNE (finite inputs)
__device__ __forceinline__ unsigned short f2bf(float f){
  unsigned u = __builtin_bit_cast(unsigned, f);
  u = (u + 0x7FFFu + ((u >> 16) & 1u)) >> 16;
  return (unsigned short)u;
}

#if defined(__has_builtin)
#  if __has_builtin(__builtin_amdgcn_fdot2)
#    define FDOT2(a,b,c) __builtin_amdgcn_fdot2((a),(b),(c),false)
#  endif
#endif
#ifndef FDOT2
__device__ __forceinline__ float fdot2_sw(half2v a, half2v b, float c){
  return c + (float)a[0]*(float)b[0] + (float)a[1]*(float)b[1];
}
#  define FDOT2(a,b,c) fdot2_sw((a),(b),(c))
#endif

// tanh-form GELU using HW v_exp_f32. Abs error vs exact-erf GELU ~3e-3
// (does NOT scale with |x|; exact in linear regime). Overflow-safe:
// exp(large)=inf -> 2/inf=0 -> tanh=+-1.
__device__ __forceinline__ float gelu_fast(float x){
  float u = 0.7978845608f * x * __builtin_fmaf(0.044715f, x * x, 1.0f);
  float e = __expf(2.0f * __builtin_fabsf(u));
  float t = 1.0f - 2.0f / (e + 1.0f);          // tanh(|u|)
  t = __builtin_copysignf(t, u);
  return 0.5f * x * (1.0f + t);
}

// stable softplus with HW exp/log
__device__ __forceinline__ float softplus_fast(float x){
  float e = __expf(-__builtin_fabsf(x));
  return fmaxf(x, 0.0f) + __logf(1.0f + e);
}

// ---------- kernel 0: pack mix_w into MFMA B-fragment order (bf16) ----------
// Wt[K=j*16+d][N=i*16+k] = mix_w[i][j][k][d];  frag f = ntile*4 + kstep,
// lane L holds B[k = kstep*32 + (L>>4)*8 + j][n = ntile*16 + (L&15)], j=0..7.
__global__ void prepack_wt(const float* __restrict__ mix_w,
                           unsigned short* __restrict__ wt){
  int tid = blockIdx.x * 256 + threadIdx.x;      // 0..2047
  int f = tid >> 6, L = tid & 63;
  int ks = f & 3, nt = f >> 2;
  int q = L >> 4, c = L & 15;
  int N = nt * 16 + c;
  int i = N >> 4, ko = N & 15;
  unsigned pk[4];
#pragma unroll
  for (int p = 0; p < 4; ++p){
    int K0 = ks * 32 + q * 8 + 2 * p;
    int K1 = K0 + 1;
    unsigned lo = f2bf(mix_w[((i*8 + (K0>>4))*16 + ko)*16 + (K0&15)]);
    unsigned hi = f2bf(mix_w[((i*8 + (K1>>4))*16 + ko)*16 + (K1&15)]);
    pk[p] = lo | (hi << 16);
  }
  uint4 v; v.x = pk[0]; v.y = pk[1]; v.z = pk[2]; v.w = pk[3];
  ((uint4*)wt)[tid] = v;
}

// ---------- main fused kernel: 64 rows per block, 256 threads (4 waves) ----------
// LDS budget: zsm 33792 + h1s 8192 + h2s 8192 + norms 2048 + gates 32
//           = 52256 B -> 3 blocks/CU (was 55808 -> 2 blocks/CU).
__global__ __launch_bounds__(256, 3)
void soft_eq_kernel(const float* __restrict__ z,
                    const float* __restrict__ w1,  const float* __restrict__ b1,
                    const float* __restrict__ w2,  const float* __restrict__ b2,
                    const float* __restrict__ w3,  const float* __restrict__ gate_bias,
                    const unsigned short* __restrict__ wt,
                    float* __restrict__ out){
  __shared__ float    zsm[64][132];     // 132: float4-aligned rows + bank-spread frag reads
  __shared__ float    normsS[64][8];
  __shared__ _Float16 h1s[64][64];      // after MLP2, region reused for scalesS
  __shared__ _Float16 h2s[64][64];      // MLP3 reads are row-broadcast: no pad needed
  __shared__ float    gatesS[8];
  float (*scalesS)[8] = (float(*)[8])h1s;   // overlay: h1s dead after MLP2

  const int t = threadIdx.x;
  const size_t base = (size_t)blockIdx.x * (64 * 128);
  const float4* zg = (const float4*)(z + base);

  // ---- stage z into LDS (fp32) + per-bundle norms via lane shuffles ----
#pragma unroll
  for (int it = 0; it < 8; ++it){
    int idx = t + it * 256;             // float4 index in [0,2048)
    float4 v = zg[idx];
    int r  = idx >> 5;                  // row in tile
    int c4 = (idx & 31) * 4;            // col (multiple of 4)
    *(float4*)&zsm[r][c4] = v;
    float ss = v.x*v.x + v.y*v.y + v.z*v.z + v.w*v.w;
    ss += __shfl_xor(ss, 1);
    ss += __shfl_xor(ss, 2);
    if ((t & 3) == 0) normsS[r][c4 >> 4] = sqrtf(ss) + 1e-8f;
  }

  // ---- register-cache per-neuron weight rows (L1-resident) ----
  const int i = t & 63;                 // neuron id for MLP1/2
  float w1r[8];
  { const float4* p = (const float4*)(w1 + i * 8);
    float4 a = p[0], bq = p[1];
    w1r[0]=a.x; w1r[1]=a.y; w1r[2]=a.z; w1r[3]=a.w;
    w1r[4]=bq.x; w1r[5]=bq.y; w1r[6]=bq.z; w1r[7]=bq.w; }
  const float b1r = b1[i], b2r = b2[i];
  half2v wreg[32];                      // w2 row (later reused for w3 row)
  { const float4* p = (const float4*)(w2 + i * 64);
#pragma unroll
    for (int kk = 0; kk < 16; ++kk){
      float4 v = p[kk];
      wreg[2*kk]   = half2v{(_Float16)v.x, (_Float16)v.y};
      wreg[2*kk+1] = half2v{(_Float16)v.z, (_Float16)v.w};
    } }
  if (t < 8) gatesS[t] = 1.0f / (1.0f + __expf(-gate_bias[t]));

  __syncthreads();

  // ---- MLP layer 1: h1 = gelu(norms @ w1^T + b1) ----
  const int rg = t >> 6;                // row-subgroup 0..3 (== wave id)
#pragma unroll
  for (int chunk = 0; chunk < 16; ++chunk){
    int r = chunk * 4 + rg;
    const float4* np = (const float4*)&normsS[r][0];   // wave-broadcast reads
    float4 n0 = np[0], n1 = np[1];
    float pre = b1r + n0.x*w1r[0] + n0.y*w1r[1] + n0.z*w1r[2] + n0.w*w1r[3]
                    + n1.x*w1r[4] + n1.y*w1r[5] + n1.z*w1r[6] + n1.w*w1r[7];
    h1s[r][i] = (_Float16)gelu_fast(pre);
  }
  __syncthreads();

  // ---- MLP layer 2: h2 = gelu(h1 @ w2^T + b2), f16 dot2, 4-way ILP ----
#pragma unroll
  for (int chunk = 0; chunk < 16; ++chunk){
    int r = chunk * 4 + rg;
    const uint4* hp = (const uint4*)&h1s[r][0];        // wave-broadcast b128 reads
    float a0 = b2r, a1 = 0.f, a2 = 0.f, a3 = 0.f;
#pragma unroll
    for (int kk = 0; kk < 8; ++kk){
      uint4 hv = hp[kk];
      a0 = FDOT2(__builtin_bit_cast(half2v, hv.x), wreg[4*kk+0], a0);
      a1 = FDOT2(__builtin_bit_cast(half2v, hv.y), wreg[4*kk+1], a1);
      a2 = FDOT2(__builtin_bit_cast(half2v, hv.z), wreg[4*kk+2], a2);
      a3 = FDOT2(__builtin_bit_cast(half2v, hv.w), wreg[4*kk+3], a3);
    }
    float accv = (a0 + a1) + (a2 + a3);
    h2s[r][i] = (_Float16)gelu_fast(accv);
  }

  // reload wreg with this thread's w3 row (register live-range reuse)
  { const float4* p = (const float4*)(w3 + (t & 7) * 64);
#pragma unroll
    for (int kk = 0; kk < 16; ++kk){
      float4 v = p[kk];
      wreg[2*kk]   = half2v{(_Float16)v.x, (_Float16)v.y};
      wreg[2*kk+1] = half2v{(_Float16)v.z, (_Float16)v.w};
    } }
  __syncthreads();

  // ---- MLP layer 3: scales = softplus(h2 @ w3^T), 4-way ILP ----
#pragma unroll
  for (int s = 0; s < 2; ++s){
    int item = s * 256 + t;
    int r = item >> 3, j = item & 7;
    const uint4* hp = (const uint4*)&h2s[r][0];        // 8-lane-group broadcast
    float a0 = 0.f, a1 = 0.f, a2 = 0.f, a3 = 0.f;
#pragma unroll
    for (int kk = 0; kk < 8; ++kk){
      uint4 hv = hp[kk];
      a0 = FDOT2(__builtin_bit_cast(half2v, hv.x), wreg[4*kk+0], a0);
      a1 = FDOT2(__builtin_bit_cast(half2v, hv.y), wreg[4*kk+1], a1);
      a2 = FDOT2(__builtin_bit_cast(half2v, hv.z), wreg[4*kk+2], a2);
      a3 = FDOT2(__builtin_bit_cast(half2v, hv.w), wreg[4*kk+3], a3);
    }
    scalesS[r][j] = softplus_fast((a0 + a1) + (a2 + a3));
  }
  __syncthreads();

  // ---- mixing GEMM: wave w owns rows 16w..16w+15; C = Ztile @ Wt ----
  const int w = t >> 6, L = t & 63, q = L >> 4, c = L & 15;
  f32x4 acc[8] = {};                    // 8 n-tiles x 4 fp32
  const uint4* wtf = (const uint4*)wt;
  const int am = w * 16 + c;            // A row (m = lane&15)
#pragma unroll
  for (int ks = 0; ks < 4; ++ks){
    int ak = ks * 32 + q * 8;           // A k-base (contiguous 8)
    float4 a0 = *(const float4*)&zsm[am][ak];
    float4 a1 = *(const float4*)&zsm[am][ak + 4];
    ushort8 au;
    au[0]=f2bf(a0.x); au[1]=f2bf(a0.y); au[2]=f2bf(a0.z); au[3]=f2bf(a0.w);
    au[4]=f2bf(a1.x); au[5]=f2bf(a1.y); au[6]=f2bf(a1.z); au[7]=f2bf(a1.w);
    bf16x8 af = __builtin_bit_cast(bf16x8, au);
#pragma unroll
    for (int n = 0; n < 8; ++n){
      uint4 bv = wtf[(n * 4 + ks) * 64 + L];           // L1-hit, coalesced
      bf16x8 bfr = __builtin_bit_cast(bf16x8, bv);
      acc[n] = __builtin_amdgcn_mfma_f32_16x16x32_bf16(af, bfr, acc[n], 0, 0, 0);
    }
  }

  // ---- epilogue straight from MFMA C-layout (wave-private rows) ----
  float* op = out + base;
#pragma unroll
  for (int n = 0; n < 8; ++n){          // n == bundle index of output col
    float gate = gatesS[n];
#pragma unroll
    for (int rr = 0; rr < 4; ++rr){
      int row = w * 16 + q * 4 + rr;    // C row = (lane>>4)*4 + reg
      int col = n * 16 + c;             // C col = lane&15
      float zv = zsm[row][col];
      float sc = scalesS[row][n];
      op[row * 128 + col] = zv + zv * sc + gate * acc[n][rr];
    }
  }
}

extern "C" void kernel_launch(void* const* d_in, const int* in_sizes, int n_in,
                              void* d_out, int out_size, void* d_ws, size_t ws_size,
                              hipStream_t stream){
  const float* z         = (const float*)d_in[0];
  const float* w1        = (const float*)d_in[1];
  const float* b1        = (const float*)d_in[2];
  const float* w2        = (const float*)d_in[3];
  const float* b2        = (const float*)d_in[4];
  const float* w3        = (const float*)d_in[5];
  const float* mix_w     = (const float*)d_in[6];
  const float* gate_bias = (const float*)d_in[7];
  float* out = (float*)d_out;
  unsigned short* wt = (unsigned short*)d_ws;   // 32 KiB B-fragment cache

  int B = in_sizes[0] / 128;                    // rows
  prepack_wt<<<8, 256, 0, stream>>>(mix_w, wt);
  soft_eq_kernel<<<B / 64, 256, 0, stream>>>(z, w1, b1, w2, b2, w3, gate_bias, wt, out);
}